// Round 1
// baseline (479.892 us; speedup 1.0000x reference)
//
#include <hip/hip_runtime.h>

// LinearAttention: B=4, T=8192, D=512, H=8, DH=64, M=B*T=32768
// Pipeline: proj(q,k,v) -> ctx/ksum -> num/den/div -> out-proj
// bf16 MFMA for the 4 big GEMMs, f32 VALU for the attention core.

typedef float v4f __attribute__((ext_vector_type(4)));
typedef short v8s __attribute__((ext_vector_type(8)));

__device__ __forceinline__ ushort f2bf(float f) {
  unsigned u = __float_as_uint(f);
  u += 0x7FFFu + ((u >> 16) & 1u);  // RNE
  return (ushort)(u >> 16);
}
__device__ __forceinline__ float bf2f(ushort h) {
  return __uint_as_float(((unsigned)h) << 16);
}
__device__ __forceinline__ unsigned pk2(float a, float b) {
  return (unsigned)f2bf(a) | ((unsigned)f2bf(b) << 16);
}

// ---------------- projection GEMM: Y = act(X @ W^T + b) -> bf16 -------------
// grid: (4 n-blocks, 256 m-blocks, 3 inputs), block 256 (4 waves, 64x64 each)
__global__ __launch_bounds__(256) void proj_kernel(
    const float* __restrict__ X0, const float* __restrict__ X1, const float* __restrict__ X2,
    const float* __restrict__ W0, const float* __restrict__ W1, const float* __restrict__ W2,
    const float* __restrict__ Bb0, const float* __restrict__ Bb1, const float* __restrict__ Bb2,
    ushort* __restrict__ Y0, ushort* __restrict__ Y1, ushort* __restrict__ Y2) {
  __shared__ char As[16384];  // [128 rows][64 k] bf16, XOR-swizzled 16B blocks
  __shared__ char Bs[16384];
  const int z = blockIdx.z;
  const float* __restrict__ X  = (z == 0) ? X0  : (z == 1) ? X1  : X2;
  const float* __restrict__ W  = (z == 0) ? W0  : (z == 1) ? W1  : W2;
  const float* __restrict__ Bb = (z == 0) ? Bb0 : (z == 1) ? Bb1 : Bb2;
  ushort* __restrict__ Y       = (z == 0) ? Y0  : (z == 1) ? Y1  : Y2;
  const bool do_elu = (z < 2);

  const int tid = threadIdx.x;
  const int lane = tid & 63;
  const int wv = tid >> 6;
  const int wr = wv >> 1, wc = wv & 1;
  const int n0 = blockIdx.x * 128;
  const int m0 = blockIdx.y * 128;

  const v4f vzero = {0.f, 0.f, 0.f, 0.f};
  v4f acc[4][4];
#pragma unroll
  for (int i = 0; i < 4; ++i)
#pragma unroll
    for (int j = 0; j < 4; ++j) acc[i][j] = vzero;

  for (int k0 = 0; k0 < 512; k0 += 64) {
    __syncthreads();
    // stage A: 128x64 f32 -> bf16 swizzled
#pragma unroll
    for (int r = 0; r < 8; ++r) {
      int s = tid + (r << 8);
      int row = s >> 4;
      int kq = (s & 15) << 2;
      v4f xv = *reinterpret_cast<const v4f*>(X + (size_t)(m0 + row) * 512 + k0 + kq);
      ushort4 hv = make_ushort4(f2bf(xv[0]), f2bf(xv[1]), f2bf(xv[2]), f2bf(xv[3]));
      int off = (row << 7) + (((kq >> 3) ^ (row & 7)) << 4) + ((kq & 7) << 1);
      *reinterpret_cast<ushort4*>(As + off) = hv;
    }
    // stage B (= W rows, already B^T layout)
#pragma unroll
    for (int r = 0; r < 8; ++r) {
      int s = tid + (r << 8);
      int row = s >> 4;
      int kq = (s & 15) << 2;
      v4f wvv = *reinterpret_cast<const v4f*>(W + (size_t)(n0 + row) * 512 + k0 + kq);
      ushort4 hv = make_ushort4(f2bf(wvv[0]), f2bf(wvv[1]), f2bf(wvv[2]), f2bf(wvv[3]));
      int off = (row << 7) + (((kq >> 3) ^ (row & 7)) << 4) + ((kq & 7) << 1);
      *reinterpret_cast<ushort4*>(Bs + off) = hv;
    }
    __syncthreads();
#pragma unroll
    for (int kk = 0; kk < 2; ++kk) {
      const int kq = (kk << 5) + ((lane >> 4) << 3);
      const int kb = kq >> 3;
      v8s af[4], bfr[4];
#pragma unroll
      for (int mi = 0; mi < 4; ++mi) {
        int row = (wr << 6) + (mi << 4) + (lane & 15);
        af[mi] = *reinterpret_cast<const v8s*>(As + (row << 7) + ((kb ^ (row & 7)) << 4));
      }
#pragma unroll
      for (int ni = 0; ni < 4; ++ni) {
        int col = (wc << 6) + (ni << 4) + (lane & 15);
        bfr[ni] = *reinterpret_cast<const v8s*>(Bs + (col << 7) + ((kb ^ (col & 7)) << 4));
      }
#pragma unroll
      for (int mi = 0; mi < 4; ++mi)
#pragma unroll
        for (int ni = 0; ni < 4; ++ni)
          acc[mi][ni] = __builtin_amdgcn_mfma_f32_16x16x32_bf16(af[mi], bfr[ni], acc[mi][ni], 0, 0, 0);
    }
  }

  // epilogue: bias + (elu(x)+1) for q,k; identity for v. C/D: col=lane&15, row=(lane>>4)*4+j
#pragma unroll
  for (int ni = 0; ni < 4; ++ni) {
    const int col = n0 + (wc << 6) + (ni << 4) + (lane & 15);
    const float bv = Bb[col];
#pragma unroll
    for (int mi = 0; mi < 4; ++mi) {
#pragma unroll
      for (int j = 0; j < 4; ++j) {
        int row = m0 + (wr << 6) + (mi << 4) + ((lane >> 4) << 2) + j;
        float zv = acc[mi][ni][j] + bv;
        float val = do_elu ? ((zv > 0.f) ? (zv + 1.f) : __expf(zv)) : zv;
        Y[(size_t)row * 512 + col] = f2bf(val);
      }
    }
  }
}

// ---------------- ctx[bh][c][d] = sum_t kh*vh ; ksum[bh][c] ------------------
// grid: (16 chunks of 512 t, 32 bh), block 256; f32 atomics into zeroed ws
__global__ __launch_bounds__(256) void ctx_kernel(
    const ushort* __restrict__ KH, const ushort* __restrict__ VH,
    float* __restrict__ CTX, float* __restrict__ KSUM) {
  __shared__ ushort kl[4096];
  __shared__ ushort vl[4096];
  const int tid = threadIdx.x;
  const int bh = blockIdx.y;
  const int b = bh >> 3, h = bh & 7;
  const int t0 = blockIdx.x << 9;
  const int c0 = (tid >> 4) << 2;
  const int d0 = (tid & 15) << 2;
  float acc[4][4];
#pragma unroll
  for (int i = 0; i < 4; ++i)
#pragma unroll
    for (int j = 0; j < 4; ++j) acc[i][j] = 0.f;
  float ks = 0.f;

  for (int sub = 0; sub < 8; ++sub) {
    __syncthreads();
#pragma unroll
    for (int r = 0; r < 2; ++r) {
      int s = tid + (r << 8);
      int row = s >> 3;
      int cb = (s & 7) << 3;
      size_t src = ((size_t)(b * 8192 + t0 + (sub << 6) + row)) * 512 + (h << 6) + cb;
      *reinterpret_cast<uint4*>(&kl[(row << 6) + cb]) = *reinterpret_cast<const uint4*>(KH + src);
      *reinterpret_cast<uint4*>(&vl[(row << 6) + cb]) = *reinterpret_cast<const uint4*>(VH + src);
    }
    __syncthreads();
#pragma unroll 4
    for (int t = 0; t < 64; ++t) {
      ushort4 kv = *reinterpret_cast<const ushort4*>(&kl[(t << 6) + c0]);
      ushort4 vv = *reinterpret_cast<const ushort4*>(&vl[(t << 6) + d0]);
      float ka[4] = {bf2f(kv.x), bf2f(kv.y), bf2f(kv.z), bf2f(kv.w)};
      float va[4] = {bf2f(vv.x), bf2f(vv.y), bf2f(vv.z), bf2f(vv.w)};
#pragma unroll
      for (int i = 0; i < 4; ++i)
#pragma unroll
        for (int j = 0; j < 4; ++j) acc[i][j] += ka[i] * va[j];
    }
    if (tid < 64) {
#pragma unroll 8
      for (int t = 0; t < 64; ++t) ks += bf2f(kl[(t << 6) + tid]);
    }
  }
#pragma unroll
  for (int i = 0; i < 4; ++i)
#pragma unroll
    for (int j = 0; j < 4; ++j)
      atomicAdd(&CTX[(bh << 12) + ((c0 + i) << 6) + (d0 + j)], acc[i][j]);
  if (tid < 64) atomicAdd(&KSUM[(bh << 6) + tid], ks);
}

// ---------------- o = (qh @ ctx) / (qh . ksum) -> bf16 ----------------------
// grid: (64 tiles of 128 t, 32 bh), block 256; wave w owns 16 d's, lane owns 2 t's
__global__ __launch_bounds__(256) void numdiv_kernel(
    const ushort* __restrict__ QH, const float* __restrict__ CTX,
    const float* __restrict__ KSUM, ushort* __restrict__ O) {
  __shared__ float ctxl[4096];
  __shared__ float ksl[64];
  __shared__ ushort qtl[64 * 138];  // qh^T [c][t], t-stride 138 to spread banks
  const int tid = threadIdx.x;
  const int bh = blockIdx.y;
  const int b = bh >> 3, h = bh & 7;
  const int t0 = blockIdx.x << 7;

#pragma unroll
  for (int r = 0; r < 4; ++r) {
    int s = tid + (r << 8);
    int row = s >> 4;
    int c4 = (s & 15) << 2;
    *reinterpret_cast<v4f*>(&ctxl[(row << 6) + c4]) =
        *reinterpret_cast<const v4f*>(&CTX[(bh << 12) + (row << 6) + c4]);
  }
  if (tid < 64) ksl[tid] = KSUM[(bh << 6) + tid];
#pragma unroll
  for (int r = 0; r < 4; ++r) {
    int s = tid + (r << 8);
    int trow = s >> 3;
    int cb = (s & 7) << 3;
    uint4 raw = *reinterpret_cast<const uint4*>(
        QH + ((size_t)(b * 8192 + t0 + trow)) * 512 + (h << 6) + cb);
    const ushort* p = reinterpret_cast<const ushort*>(&raw);
#pragma unroll
    for (int i = 0; i < 8; ++i) qtl[(cb + i) * 138 + trow] = p[i];
  }
  __syncthreads();

  const int l = tid & 63;
  const int dw = (tid >> 6) << 4;
  float a0[16], a1[16];
#pragma unroll
  for (int j = 0; j < 16; ++j) { a0[j] = 0.f; a1[j] = 0.f; }
  float den0 = 0.f, den1 = 0.f;

  for (int c = 0; c < 64; ++c) {
    float q0 = bf2f(qtl[c * 138 + l]);
    float q1 = bf2f(qtl[c * 138 + 64 + l]);
    float kv = ksl[c];
    den0 += q0 * kv;
    den1 += q1 * kv;
#pragma unroll
    for (int p4 = 0; p4 < 4; ++p4) {
      v4f cv = *reinterpret_cast<const v4f*>(&ctxl[(c << 6) + dw + (p4 << 2)]);
#pragma unroll
      for (int jj = 0; jj < 4; ++jj) {
        a0[(p4 << 2) + jj] += q0 * cv[jj];
        a1[(p4 << 2) + jj] += q1 * cv[jj];
      }
    }
  }
  float i0 = 1.f / den0, i1 = 1.f / den1;
  {
    size_t ro = ((size_t)(b * 8192 + t0 + l)) * 512 + (h << 6) + dw;
    uint4 w0 = make_uint4(pk2(a0[0] * i0, a0[1] * i0), pk2(a0[2] * i0, a0[3] * i0),
                          pk2(a0[4] * i0, a0[5] * i0), pk2(a0[6] * i0, a0[7] * i0));
    uint4 w1 = make_uint4(pk2(a0[8] * i0, a0[9] * i0), pk2(a0[10] * i0, a0[11] * i0),
                          pk2(a0[12] * i0, a0[13] * i0), pk2(a0[14] * i0, a0[15] * i0));
    *reinterpret_cast<uint4*>(O + ro) = w0;
    *reinterpret_cast<uint4*>(O + ro + 8) = w1;
  }
  {
    size_t ro = ((size_t)(b * 8192 + t0 + 64 + l)) * 512 + (h << 6) + dw;
    uint4 w0 = make_uint4(pk2(a1[0] * i1, a1[1] * i1), pk2(a1[2] * i1, a1[3] * i1),
                          pk2(a1[4] * i1, a1[5] * i1), pk2(a1[6] * i1, a1[7] * i1));
    uint4 w1 = make_uint4(pk2(a1[8] * i1, a1[9] * i1), pk2(a1[10] * i1, a1[11] * i1),
                          pk2(a1[12] * i1, a1[13] * i1), pk2(a1[14] * i1, a1[15] * i1));
    *reinterpret_cast<uint4*>(O + ro) = w0;
    *reinterpret_cast<uint4*>(O + ro + 8) = w1;
  }
}

// ---------------- out = o @ Wo^T + bo -> f32 --------------------------------
__global__ __launch_bounds__(256) void out_kernel(
    const ushort* __restrict__ O, const float* __restrict__ Wo,
    const float* __restrict__ bo, float* __restrict__ OUT) {
  __shared__ char As[16384];
  __shared__ char Bs[16384];
  const int tid = threadIdx.x;
  const int lane = tid & 63;
  const int wv = tid >> 6;
  const int wr = wv >> 1, wc = wv & 1;
  const int n0 = blockIdx.x * 128;
  const int m0 = blockIdx.y * 128;

  const v4f vzero = {0.f, 0.f, 0.f, 0.f};
  v4f acc[4][4];
#pragma unroll
  for (int i = 0; i < 4; ++i)
#pragma unroll
    for (int j = 0; j < 4; ++j) acc[i][j] = vzero;

  for (int k0 = 0; k0 < 512; k0 += 64) {
    __syncthreads();
    // stage A (bf16 already): 16B chunks, swizzled
#pragma unroll
    for (int r = 0; r < 4; ++r) {
      int s = tid + (r << 8);
      int row = s >> 3;
      int kc = (s & 7) << 3;
      uint4 raw = *reinterpret_cast<const uint4*>(O + (size_t)(m0 + row) * 512 + k0 + kc);
      int off = (row << 7) + (((kc >> 3) ^ (row & 7)) << 4);
      *reinterpret_cast<uint4*>(As + off) = raw;
    }
#pragma unroll
    for (int r = 0; r < 8; ++r) {
      int s = tid + (r << 8);
      int row = s >> 4;
      int kq = (s & 15) << 2;
      v4f wvv = *reinterpret_cast<const v4f*>(Wo + (size_t)(n0 + row) * 512 + k0 + kq);
      ushort4 hv = make_ushort4(f2bf(wvv[0]), f2bf(wvv[1]), f2bf(wvv[2]), f2bf(wvv[3]));
      int off = (row << 7) + (((kq >> 3) ^ (row & 7)) << 4) + ((kq & 7) << 1);
      *reinterpret_cast<ushort4*>(Bs + off) = hv;
    }
    __syncthreads();
#pragma unroll
    for (int kk = 0; kk < 2; ++kk) {
      const int kq = (kk << 5) + ((lane >> 4) << 3);
      const int kb = kq >> 3;
      v8s af[4], bfr[4];
#pragma unroll
      for (int mi = 0; mi < 4; ++mi) {
        int row = (wr << 6) + (mi << 4) + (lane & 15);
        af[mi] = *reinterpret_cast<const v8s*>(As + (row << 7) + ((kb ^ (row & 7)) << 4));
      }
#pragma unroll
      for (int ni = 0; ni < 4; ++ni) {
        int col = (wc << 6) + (ni << 4) + (lane & 15);
        bfr[ni] = *reinterpret_cast<const v8s*>(Bs + (col << 7) + ((kb ^ (col & 7)) << 4));
      }
#pragma unroll
      for (int mi = 0; mi < 4; ++mi)
#pragma unroll
        for (int ni = 0; ni < 4; ++ni)
          acc[mi][ni] = __builtin_amdgcn_mfma_f32_16x16x32_bf16(af[mi], bfr[ni], acc[mi][ni], 0, 0, 0);
    }
  }

#pragma unroll
  for (int ni = 0; ni < 4; ++ni) {
    const int col = n0 + (wc << 6) + (ni << 4) + (lane & 15);
    const float bv = bo[col];
#pragma unroll
    for (int mi = 0; mi < 4; ++mi) {
#pragma unroll
      for (int j = 0; j < 4; ++j) {
        int row = m0 + (wr << 6) + (mi << 4) + ((lane >> 4) << 2) + j;
        OUT[(size_t)row * 512 + col] = acc[mi][ni][j] + bv;
      }
    }
  }
}

extern "C" void kernel_launch(void* const* d_in, const int* in_sizes, int n_in,
                              void* d_out, int out_size, void* d_ws, size_t ws_size,
                              hipStream_t stream) {
  const float* q  = (const float*)d_in[0];
  const float* k  = (const float*)d_in[1];
  const float* v  = (const float*)d_in[2];
  const float* Wq = (const float*)d_in[3];
  const float* bq = (const float*)d_in[4];
  const float* Wk = (const float*)d_in[5];
  const float* bk = (const float*)d_in[6];
  const float* Wv = (const float*)d_in[7];
  const float* bv = (const float*)d_in[8];
  const float* Wo = (const float*)d_in[9];
  const float* bo = (const float*)d_in[10];
  float* out = (float*)d_out;

  // workspace layout (bytes): qh | kh | vh | ctx | ksum ; o aliases qh (safe:
  // numdiv blocks stage their exact read region to LDS before overwriting it)
  char* ws = (char*)d_ws;
  const size_t SZ = 32768ull * 512ull * 2ull;  // 33,554,432 bytes per bf16 buffer
  ushort* qh = (ushort*)(ws);
  ushort* kh = (ushort*)(ws + SZ);
  ushort* vh = (ushort*)(ws + 2 * SZ);
  ushort* o  = qh;  // alias
  float* ctx  = (float*)(ws + 3 * SZ);                 // 32*64*64 f32 = 512 KB
  float* ksum = (float*)(ws + 3 * SZ + 524288);        // 32*64 f32 = 8 KB

  hipMemsetAsync(ws + 3 * SZ, 0, 524288 + 8192, stream);

  proj_kernel<<<dim3(4, 256, 3), 256, 0, stream>>>(q, k, v, Wq, Wk, Wv, bq, bk, bv, qh, kh, vh);
  ctx_kernel<<<dim3(16, 32), 256, 0, stream>>>(kh, vh, ctx, ksum);
  numdiv_kernel<<<dim3(64, 32), 256, 0, stream>>>(qh, ctx, ksum, o);
  out_kernel<<<dim3(4, 256), 256, 0, stream>>>(o, Wo, bo, out);
}